// Round 17
// baseline (609.779 us; speedup 1.0000x reference)
//
#include <hip/hip_runtime.h>

#define N_NODES 10000
#define N_EDGES 320000
#define IN_F    512
#define H1F     256
#define H2F     64

typedef __attribute__((ext_vector_type(8)))  short short8;   // 8 x bf16 (4 VGPRs)
typedef __attribute__((ext_vector_type(16))) float f32x16;   // MFMA 32x32 accumulator
typedef __attribute__((ext_vector_type(4)))  float f32x4;    // native float4 for nt stores

__device__ __forceinline__ unsigned short f2bf(float f) {
    union { float fl; unsigned int i; } v; v.fl = f;
    unsigned int x = v.i;
    return (unsigned short)((x + 0x7fffu + ((x >> 16) & 1u)) >> 16);
}
__device__ __forceinline__ float bf2f(unsigned short u) {
    union { unsigned int i; float f; } v; v.i = ((unsigned int)u) << 16; return v.f;
}
// dict order (ew,src,dst): c0=float weight, int-reinterp never in [0,N_NODES)
// (only denormals); alpha order (dst,src,ew): c0=dst always is.
__device__ __forceinline__ bool edge_is_alpha(int a0) {
    return (unsigned)a0 < N_NODES;
}

// ---------- CSR build: histogram -> scan -> bucket (packed (src,w)) ----------
__global__ __launch_bounds__(256) void k_hist(const int* __restrict__ c0,
                                              const int* __restrict__ c2,
                                              int* __restrict__ deg) {
    int e = blockIdx.x * 256 + threadIdx.x;
    if (e >= N_EDGES) return;
    int a0 = c0[e];
    int dst = edge_is_alpha(a0) ? a0 : c2[e];
    if ((unsigned)dst < N_NODES) atomicAdd(&deg[dst], 1);
}

__global__ __launch_bounds__(1024) void k_scan(const int* __restrict__ deg,
                                               int* __restrict__ off,
                                               int* __restrict__ cursor) {
    __shared__ int part[1024];
    int t = threadIdx.x;
    const int chunk = (N_NODES + 1023) / 1024;  // 10
    int begin = t * chunk;
    int end = begin + chunk; if (end > N_NODES) end = N_NODES;
    if (begin > N_NODES) begin = N_NODES;
    int s = 0;
    for (int i = begin; i < end; ++i) s += deg[i];
    part[t] = s;
    __syncthreads();
    for (int o = 1; o < 1024; o <<= 1) {
        int v = (t >= o) ? part[t - o] : 0;
        __syncthreads();
        part[t] += v;
        __syncthreads();
    }
    int base = (t == 0) ? 0 : part[t - 1];
    for (int i = begin; i < end; ++i) {
        off[i] = base; cursor[i] = base; base += deg[i];
    }
    if (t == 1023) off[N_NODES] = part[1023];
}

__global__ __launch_bounds__(256) void k_bucket(const int* __restrict__ c0,
                                                const int* __restrict__ c1,
                                                const int* __restrict__ c2,
                                                const float* __restrict__ c0f,
                                                const float* __restrict__ c2f,
                                                int* __restrict__ cursor,
                                                int2* __restrict__ ep) {
    int e = blockIdx.x * 256 + threadIdx.x;
    if (e >= N_EDGES) return;
    int a0 = c0[e];
    bool alpha = edge_is_alpha(a0);
    int src = c1[e];
    int dst = alpha ? a0 : c2[e];
    float w = alpha ? c2f[e] : c0f[e];
    if ((unsigned)src >= N_NODES || (unsigned)dst >= N_NODES) return;
    int p = atomicAdd(&cursor[dst], 1);
    ep[p] = make_int2(src, __float_as_int(w));
}

// ---------- GEMM1: sup1b[10000,256] (bf16) = x @ W1, 16 nodes/block ----------
// 16 nodes/block halves W1 re-reads (640->320 MB) and doubles FMA per W1 load.
__global__ __launch_bounds__(256) void k_gemm1(const float* __restrict__ x,
                                               const float* __restrict__ W1,
                                               unsigned short* __restrict__ sup1b) {
    __shared__ float xs[IN_F][16];   // 32 KB, [k][node]
    int nb = blockIdx.x * 16;
    int t = threadIdx.x;
    {
        int n  = t & 15;
        int k0 = (t >> 4) * 32;      // 16 threads/node, 32 k each
        const float* xr = x + (size_t)(nb + n) * IN_F + k0;
        #pragma unroll
        for (int c = 0; c < 32; c += 4) {
            float4 v = *(const float4*)(xr + c);
            xs[k0 + c + 0][n] = v.x;
            xs[k0 + c + 1][n] = v.y;
            xs[k0 + c + 2][n] = v.z;
            xs[k0 + c + 3][n] = v.w;
        }
    }
    __syncthreads();
    int f = t;
    float acc[16];
    #pragma unroll
    for (int n = 0; n < 16; ++n) acc[n] = 0.f;
    #pragma unroll 4
    for (int k = 0; k < IN_F; ++k) {
        float w = W1[(size_t)k * H1F + f];      // coalesced across lanes
        #pragma unroll
        for (int q = 0; q < 4; ++q) {
            float4 a = *(const float4*)&xs[k][q * 4];   // broadcast (same addr all lanes)
            acc[q*4+0] += a.x * w; acc[q*4+1] += a.y * w;
            acc[q*4+2] += a.z * w; acc[q*4+3] += a.w * w;
        }
    }
    #pragma unroll
    for (int n = 0; n < 16; ++n)
        sup1b[(size_t)(nb + n) * H1F + f] = f2bf(acc[n]);
}

// ---------- agg1: LDS-staged edges, 4-way unrolled independent gathers ----------
__global__ __launch_bounds__(256) void k_agg1(const unsigned short* __restrict__ sup1b,
                                              const int* __restrict__ off,
                                              const int2* __restrict__ ep,
                                              const float* __restrict__ b1,
                                              float* __restrict__ h1) {
    __shared__ int2 eds[256];
    int node = blockIdx.x;
    int f = threadIdx.x;
    int s = off[node], e = off[node + 1];
    float a0 = 0.f, a1 = 0.f, a2 = 0.f, a3 = 0.f;
    for (int base = s; base < e; base += 256) {
        int n = e - base; if (n > 256) n = 256;
        __syncthreads();
        if (f < n) eds[f] = ep[base + f];
        __syncthreads();
        int j = 0;
        for (; j + 4 <= n; j += 4) {
            int2 e0 = eds[j], e1 = eds[j+1], e2 = eds[j+2], e3 = eds[j+3];
            a0 += __int_as_float(e0.y) * bf2f(sup1b[(size_t)e0.x * H1F + f]);
            a1 += __int_as_float(e1.y) * bf2f(sup1b[(size_t)e1.x * H1F + f]);
            a2 += __int_as_float(e2.y) * bf2f(sup1b[(size_t)e2.x * H1F + f]);
            a3 += __int_as_float(e3.y) * bf2f(sup1b[(size_t)e3.x * H1F + f]);
        }
        for (; j < n; ++j) {
            int2 e0 = eds[j];
            a0 += __int_as_float(e0.y) * bf2f(sup1b[(size_t)e0.x * H1F + f]);
        }
    }
    float acc = (a0 + a1) + (a2 + a3);
    h1[(size_t)node * H1F + f] = fmaxf(acc + b1[f], 0.f);
}

// ---------- GEMM2: sup2[10000,64] = h1 @ W2, 4 nodes/block (fp32) ----------
__global__ __launch_bounds__(64) void k_gemm2(const float* __restrict__ h1,
                                              const float* __restrict__ W2,
                                              float* __restrict__ sup2) {
    __shared__ float hs[H1F][4];
    int nb = blockIdx.x * 4;
    int t = threadIdx.x;
    {
        int n  = t & 3;
        int k0 = (t >> 2) * 16;
        const float* hr = h1 + (size_t)(nb + n) * H1F + k0;
        #pragma unroll
        for (int c = 0; c < 16; c += 4) {
            float4 v = *(const float4*)(hr + c);
            hs[k0 + c + 0][n] = v.x;
            hs[k0 + c + 1][n] = v.y;
            hs[k0 + c + 2][n] = v.z;
            hs[k0 + c + 3][n] = v.w;
        }
    }
    __syncthreads();
    int f = t;
    float acc[4] = {0.f,0.f,0.f,0.f};
    #pragma unroll 8
    for (int k = 0; k < H1F; ++k) {
        float w = W2[(size_t)k * H2F + f];
        float4 a = *(const float4*)&hs[k][0];
        acc[0] += a.x * w; acc[1] += a.y * w; acc[2] += a.z * w; acc[3] += a.w * w;
    }
    #pragma unroll
    for (int n = 0; n < 4; ++n)
        sup2[(size_t)(nb + n) * H2F + f] = acc[n];
}

// ---------- agg2: LDS-staged, unrolled; z fp32 (d_out) + bf16 zb (ws) ----------
__global__ __launch_bounds__(64) void k_agg2(const float* __restrict__ sup2,
                                             const int* __restrict__ off,
                                             const int2* __restrict__ ep,
                                             const float* __restrict__ b2,
                                             float* __restrict__ zout,
                                             unsigned short* __restrict__ zb) {
    __shared__ int2 eds[64];
    int node = blockIdx.x;
    int f = threadIdx.x;
    int s = off[node], e = off[node + 1];
    float a0 = 0.f, a1 = 0.f, a2 = 0.f, a3 = 0.f;
    for (int base = s; base < e; base += 64) {
        int n = e - base; if (n > 64) n = 64;
        __syncthreads();
        if (f < n) eds[f] = ep[base + f];
        __syncthreads();
        int j = 0;
        for (; j + 4 <= n; j += 4) {
            int2 e0 = eds[j], e1 = eds[j+1], e2 = eds[j+2], e3 = eds[j+3];
            a0 += __int_as_float(e0.y) * sup2[(size_t)e0.x * H2F + f];
            a1 += __int_as_float(e1.y) * sup2[(size_t)e1.x * H2F + f];
            a2 += __int_as_float(e2.y) * sup2[(size_t)e2.x * H2F + f];
            a3 += __int_as_float(e3.y) * sup2[(size_t)e3.x * H2F + f];
        }
        for (; j < n; ++j) {
            int2 e0 = eds[j];
            a0 += __int_as_float(e0.y) * sup2[(size_t)e0.x * H2F + f];
        }
    }
    float acc = (a0 + a1) + (a2 + a3);
    acc = fmaxf(acc + b2[f], 0.f);
    zout[(size_t)node * H2F + f] = acc;
    zb[(size_t)node * H2F + f] = f2bf(acc);
}

// ---------- decoder: symmetric Gram, LDS-staged tile, NONTEMPORAL stores ----------
// recon is write-once/never-read: nt stores bypass L2 write-allocate (no pollution).
// C/D layout (HW-verified): col = lane&31, row = (reg&3) + 8*(reg>>2) + 4*(lane>>5)
__global__ __launch_bounds__(256) void k_decoder(const unsigned short* __restrict__ zb,
                                                 float* __restrict__ recon) {
    int bi = blockIdx.y, bj = blockIdx.x;
    if (bj < bi) return;                      // mirror writes cover the lower triangle
    __shared__ float Cs[64][65];              // +1 pad: transposed reads conflict-free
    int t = threadIdx.x;
    int wave = t >> 6, lane = t & 63;
    int wi = (wave >> 1) * 32, wj = (wave & 1) * 32;
    int i0 = bi * 64 + wi, j0 = bj * 64 + wj;
    int r = lane & 31, half = lane >> 5;
    int arow = i0 + r, brow = j0 + r;

    short8 zero8 = {0,0,0,0,0,0,0,0};
    short8 a[4], b[4];
    #pragma unroll
    for (int s = 0; s < 4; ++s) {
        a[s] = (arow < N_NODES) ? *(const short8*)(zb + (size_t)arow * H2F + s * 16 + half * 8)
                                : zero8;
        b[s] = (brow < N_NODES) ? *(const short8*)(zb + (size_t)brow * H2F + s * 16 + half * 8)
                                : zero8;
    }
    f32x16 acc;
    #pragma unroll
    for (int i = 0; i < 16; ++i) acc[i] = 0.f;
    #pragma unroll
    for (int s = 0; s < 4; ++s)
        acc = __builtin_amdgcn_mfma_f32_32x32x16_bf16(a[s], b[s], acc, 0, 0, 0);

    // sigmoid once, into LDS tile
    #pragma unroll
    for (int rg = 0; rg < 16; ++rg) {
        int lr = wi + (rg & 3) + 8 * (rg >> 2) + 4 * half;
        int lc = wj + r;
        Cs[lr][lc] = 1.0f / (1.0f + __expf(-acc[rg]));
    }
    __syncthreads();

    // straight write
    #pragma unroll
    for (int p = 0; p < 4; ++p) {
        int e = p * 1024 + t * 4;
        int lr = e >> 6, lc = e & 63;
        int grow = bi * 64 + lr, gcol = bj * 64 + lc;
        if (grow < N_NODES) {
            f32x4 v = *(const f32x4*)&Cs[lr][lc];
            size_t base = (size_t)grow * N_NODES + gcol;
            if (gcol + 4 <= N_NODES) {
                __builtin_nontemporal_store(v, (f32x4*)&recon[base]);
            } else {
                for (int k = 0; k < 4; ++k)
                    if (gcol + k < N_NODES)
                        __builtin_nontemporal_store(v[k], &recon[base + k]);
            }
        }
    }
    // mirror (transposed) write into block (bj, bi); diagonal written once above
    if (bi != bj) {
        #pragma unroll
        for (int p = 0; p < 4; ++p) {
            int e = p * 1024 + t * 4;
            int lr = e >> 6, lc = e & 63;
            int grow = bj * 64 + lr, gcol = bi * 64 + lc;
            if (grow < N_NODES) {
                f32x4 v;
                v[0] = Cs[lc][lr]; v[1] = Cs[lc+1][lr]; v[2] = Cs[lc+2][lr]; v[3] = Cs[lc+3][lr];
                size_t base = (size_t)grow * N_NODES + gcol;
                if (gcol + 4 <= N_NODES) {
                    __builtin_nontemporal_store(v, (f32x4*)&recon[base]);
                } else {
                    for (int k = 0; k < 4; ++k)
                        if (gcol + k < N_NODES)
                            __builtin_nontemporal_store(v[k], &recon[base + k]);
                }
            }
        }
    }
}

extern "C" void kernel_launch(void* const* d_in, const int* in_sizes, int n_in,
                              void* d_out, int out_size, void* d_ws, size_t ws_size,
                              hipStream_t stream) {
    int ix = -1, iW1 = -1, ib1 = -1, iW2 = -1, ib2 = -1, ic0 = -1, ic1 = -1, ic2 = -1;
    for (int i = 0; i < n_in; ++i) {
        int s = in_sizes[i];
        if      (s == N_NODES * IN_F) ix = i;
        else if (s == IN_F * H1F)     iW1 = i;
        else if (s == H1F)            ib1 = i;
        else if (s == H1F * H2F)      iW2 = i;
        else if (s == H2F)            ib2 = i;
        else if (s == N_EDGES) { if (ic0 < 0) ic0 = i; else if (ic1 < 0) ic1 = i; else ic2 = i; }
    }
    if (ix < 0 || iW1 < 0 || ib1 < 0 || iW2 < 0 || ib2 < 0 || ic0 < 0 || ic1 < 0 || ic2 < 0) {
        ix = 0; iW1 = 1; ib1 = 2; iW2 = 3; ib2 = 4; ic0 = 5; ic1 = 6; ic2 = 7;
    }
    const float* x  = (const float*)d_in[ix];
    const float* W1 = (const float*)d_in[iW1];
    const float* b1 = (const float*)d_in[ib1];
    const float* W2 = (const float*)d_in[iW2];
    const float* b2 = (const float*)d_in[ib2];
    const int*   c0  = (const int*)d_in[ic0];
    const int*   c1  = (const int*)d_in[ic1];
    const int*   c2  = (const int*)d_in[ic2];
    const float* c0f = (const float*)d_in[ic0];
    const float* c2f = (const float*)d_in[ic2];

    float* zout  = (float*)d_out;                        // z: 640000 fp32
    float* recon = zout + (size_t)N_NODES * H2F;         // recon: 1e8 fp32 (400 MB)
    unsigned short* zb = (unsigned short*)d_ws;          // 1.28 MB (decoder input)

    // Scratch inside fp32 recon region (dead before k_decoder overwrites it).
    char* scratch = (char*)recon;
    size_t o = 0;
    auto alloc = [&](size_t bytes) { size_t p = o; o += (bytes + 255) & ~(size_t)255; return p; };
    int*            deg    = (int*)           (scratch + alloc((size_t)N_NODES * 4));
    int*            off    = (int*)           (scratch + alloc((size_t)(N_NODES + 1) * 4));
    int*            cursor = (int*)           (scratch + alloc((size_t)N_NODES * 4));
    int2*           ep     = (int2*)          (scratch + alloc((size_t)N_EDGES * 8));
    unsigned short* sup1b  = (unsigned short*)(scratch + alloc((size_t)N_NODES * H1F * 2));
    float*          h1     = (float*)         (scratch + alloc((size_t)N_NODES * H1F * 4));
    float*          sup2   = (float*)         (scratch + alloc((size_t)N_NODES * H2F * 4));

    hipMemsetAsync(deg, 0, (size_t)N_NODES * 4, stream);
    k_hist  <<<(N_EDGES + 255) / 256, 256, 0, stream>>>(c0, c2, deg);
    k_scan  <<<1, 1024, 0, stream>>>(deg, off, cursor);
    k_bucket<<<(N_EDGES + 255) / 256, 256, 0, stream>>>(c0, c1, c2, c0f, c2f, cursor, ep);

    k_gemm1<<<N_NODES / 16, 256, 0, stream>>>(x, W1, sup1b);
    k_agg1 <<<N_NODES, 256, 0, stream>>>(sup1b, off, ep, b1, h1);

    k_gemm2<<<N_NODES / 4, 64, 0, stream>>>(h1, W2, sup2);
    k_agg2 <<<N_NODES, 64, 0, stream>>>(sup2, off, ep, b2, zout, zb);

    dim3 dgrid((N_NODES + 63) / 64, (N_NODES + 63) / 64);
    k_decoder<<<dgrid, 256, 0, stream>>>(zb, recon);
}